// Round 10
// baseline (579.165 us; speedup 1.0000x reference)
//
#include <hip/hip_runtime.h>
#include <math.h>

#define H      300
#define NLEAF  4096
#define NTHR   320
#define NWAVE  5

__device__ __forceinline__ float sigmoidf_(float x) { return 1.0f / (1.0f + expf(-x)); }

// Async-stage a weight panel (R rows x 300 cols of NMAT matrices) into LDS via
// global_load_lds width 16 (fire-and-forget; drained by the next __syncthreads).
// LDS layout: [mat][row][col] flattened, NMAT*R*300 dwords, linear.
// Global rows are contiguous: b_m + (row0+r)*300 + c. All offsets 16B-aligned.
template<int NMAT>
__device__ __forceinline__ void stage_panel(const float* b0, const float* b1,
                                            int row0, int R, float* lds, int tid)
{
    const int PDh = R * 300;
    const int PD  = NMAT * PDh;
    int wave = tid >> 6, lane = tid & 63;
    const float* r0p = b0 + row0 * 300;
    const float* r1p = b1 + row0 * 300;
    for (int I = wave; I * 256 < PD; I += NWAVE) {
        int g = I * 256 + 4 * lane;
        if (g < PD) {
            const float* src = (NMAT == 2 && g >= PDh) ? (r1p + (g - PDh)) : (r0p + g);
            __builtin_amdgcn_global_load_lds(
                (const __attribute__((address_space(1))) void*)src,
                (__attribute__((address_space(3))) void*)(lds + I * 256),
                16, 0, 0);
        }
    }
}

// tag_r[t][k] = br[k] + sum_j tag_table[t][j] * Wr[300+j][k]   (likewise tag_z)
__global__ __launch_bounds__(320) void tag_kernel(
    const float* __restrict__ tag_table,
    const float* __restrict__ Wr, const float* __restrict__ br,
    const float* __restrict__ Wz, const float* __restrict__ bz,
    float* __restrict__ tag_r, float* __restrict__ tag_z)
{
    int t = blockIdx.x;
    int k = threadIdx.x;
    __shared__ float te[50];
    if (k < 50) te[k] = tag_table[t * 50 + k];
    __syncthreads();
    if (k < H) {
        float ar = br[k], az = bz[k];
        #pragma unroll 10
        for (int j = 0; j < 50; ++j) {
            float tv = te[j];
            ar = fmaf(tv, Wr[(H + j) * H + k], ar);
            az = fmaf(tv, Wz[(H + j) * H + k], az);
        }
        tag_r[t * H + k] = ar;
        tag_z[t * H + k] = az;
    }
}

// Leaf: lh=rh=0 => r unused; h = (1-z)*u. One GEMM phase:
// g=0 threads do z-cols (Wz rows 0..303), g=1 do u-cols (Wu rows 0..303).
// K padded 300->304; X pad zeroed; extra W rows are valid memory x 0.
__global__ __launch_bounds__(NTHR, 1) void leaf_k(
    const int* __restrict__ word_ids, const int* __restrict__ tag_ids,
    const float* __restrict__ word_table,
    const float* __restrict__ Wz, const float* __restrict__ Wu,
    const float* __restrict__ bu, const float* __restrict__ tag_z,
    float* __restrict__ out)
{
    constexpr int NB = 8, R = 8, NP = 38;   // K = 304 = 38*8
    __shared__ float X[NB][304];
    __shared__ float Wlds[2 * 2 * R * 300];   // dbuf x (2 mats x 8 x 300) = 9600 dwords
    int node0 = blockIdx.x * NB;
    int tid = threadIdx.x;

    for (int idx = tid; idx < NB * 76; idx += NTHR) {
        int j = idx / 76, q = idx - j * 76;
        if (q < 75)
            *(float4*)&X[j][q * 4] =
                *(const float4*)&word_table[(long)word_ids[node0 + j] * H + q * 4];
        else
            *(float4*)&X[j][300] = make_float4(0.f, 0.f, 0.f, 0.f);
    }
    stage_panel<2>(Wz, Wu, 0, R, Wlds, tid);
    __syncthreads();

    int act = (tid < 300);
    int g = (tid >= 150);
    int c0 = 2 * (tid - 150 * g);
    float acc0[NB], acc1[NB];
    #pragma unroll
    for (int j = 0; j < NB; ++j) { acc0[j] = 0.f; acc1[j] = 0.f; }

    int buf = 0;
    for (int p = 0; p < NP; ++p) {
        if (p + 1 < NP)
            stage_panel<2>(Wz, Wu, (p + 1) * R, R, Wlds + (buf ^ 1) * 4800, tid);
        if (act) {
            const float* wb = Wlds + buf * 4800 + g * 2400 + c0;
            float2 wl[R];
            #pragma unroll
            for (int i = 0; i < R; ++i) wl[i] = *(const float2*)&wb[i * 300];
            int kb = p * R;
            #pragma unroll
            for (int j = 0; j < NB; ++j) {
                float xv[8];
                *(float4*)&xv[0] = *(const float4*)&X[j][kb];
                *(float4*)&xv[4] = *(const float4*)&X[j][kb + 4];
                #pragma unroll
                for (int i = 0; i < 8; ++i) {
                    acc0[j] = fmaf(xv[i], wl[i].x, acc0[j]);
                    acc1[j] = fmaf(xv[i], wl[i].y, acc1[j]);
                }
            }
        }
        __syncthreads();
        buf ^= 1;
    }

    // z-threads publish z for all nodes via LDS; u-threads finish h.
    float* exch = Wlds;   // 300*NB dwords, staging done
    if (act && !g) {
        #pragma unroll
        for (int j = 0; j < NB; ++j) {
            int tg = tag_ids[node0 + j];
            float2 tz = *(const float2*)&tag_z[tg * H + c0];
            exch[c0 * NB + j]       = sigmoidf_(acc0[j] + tz.x);
            exch[(c0 + 1) * NB + j] = sigmoidf_(acc1[j] + tz.y);
        }
    }
    __syncthreads();
    if (act && g) {
        float b0 = bu[c0], b1 = bu[c0 + 1];
        #pragma unroll
        for (int j = 0; j < NB; ++j) {
            float u0 = tanhf(acc0[j] + b0);
            float u1 = tanhf(acc1[j] + b1);
            float z0 = exch[c0 * NB + j], z1 = exch[(c0 + 1) * NB + j];
            *(float2*)&out[(long)(node0 + j) * H + c0] =
                make_float2((1.f - z0) * u0, (1.f - z1) * u1);
        }
    }
}

// Internal level: we=0. K=600 = 75*8 panels.
// A: pre_r = [lh|rh]@Wr[350:950]+tag_r (g=0); pre_z likewise Wz (g=1).
// Exchange z/S through LDS scratch into registers, then
// B: u = tanh([r*lh|r*rh]@Wu[300:900]+bu); h = z*(lh+rh)+(1-z)*u.
template<int NB>
__global__ __launch_bounds__(NTHR, 1) void level_k(
    const int* __restrict__ tag_ids,
    const float* __restrict__ Wr, const float* __restrict__ Wz,
    const float* __restrict__ Wu, const float* __restrict__ bu,
    const float* __restrict__ tag_r, const float* __restrict__ tag_z,
    float* __restrict__ out, int off, int prevOff)
{
    constexpr int R = 8, NP = 75;
    constexpr int NBB = NB / 2;
    __shared__ float X[NB][600];
    __shared__ float Wlds[2 * 2 * R * 300];
    int node0 = blockIdx.x * NB;
    int tid = threadIdx.x;

    for (int idx = tid; idx < NB * 150; idx += NTHR) {
        int j = idx / 150, q = idx - j * 150;
        int half = q / 75, qq = q - half * 75;
        *(float4*)&X[j][half * 300 + qq * 4] =
            *(const float4*)&out[(long)(prevOff + 2 * (node0 + j) + half) * H + qq * 4];
    }
    stage_panel<2>(Wr + 350 * H, Wz + 350 * H, 0, R, Wlds, tid);
    __syncthreads();

    int act = (tid < 300);
    int g = (tid >= 150);            // 0 = r, 1 = z
    int c0 = 2 * (tid - 150 * g);
    float acc0[NB], acc1[NB];
    #pragma unroll
    for (int j = 0; j < NB; ++j) { acc0[j] = 0.f; acc1[j] = 0.f; }

    int buf = 0;
    for (int p = 0; p < NP; ++p) {
        if (p + 1 < NP)
            stage_panel<2>(Wr + 350 * H, Wz + 350 * H, (p + 1) * R, R,
                           Wlds + (buf ^ 1) * 4800, tid);
        if (act) {
            const float* wb = Wlds + buf * 4800 + g * 2400 + c0;
            float2 wl[R];
            #pragma unroll
            for (int i = 0; i < R; ++i) wl[i] = *(const float2*)&wb[i * 300];
            int kb = p * R;
            #pragma unroll
            for (int j = 0; j < NB; ++j) {
                float xv[8];
                *(float4*)&xv[0] = *(const float4*)&X[j][kb];
                *(float4*)&xv[4] = *(const float4*)&X[j][kb + 4];
                #pragma unroll
                for (int i = 0; i < 8; ++i) {
                    acc0[j] = fmaf(xv[i], wl[i].x, acc0[j]);
                    acc1[j] = fmaf(xv[i], wl[i].y, acc1[j]);
                }
            }
        }
        __syncthreads();
        buf ^= 1;
    }

    // A-epilogue + register exchange through LDS scratch.
    // exch layout [c][NB]: j<NBB holds z[j] (from z-threads), j>=NBB holds S[j] (from r-threads).
    float vS[NBB][2];   // r: own S (nodes 0..NBB-1) | z: picked S (nodes NBB..NB-1)
    float vZ[NBB][2];   // r: picked z (nodes 0..NBB-1) | z: own z (nodes NBB..NB-1)
    float* exch = Wlds;
    if (act) {
        if (!g) {
            #pragma unroll
            for (int j = 0; j < NB; ++j) {
                int tg = tag_ids[off + node0 + j];
                float2 tr = *(const float2*)&tag_r[tg * H + c0];
                float r0 = sigmoidf_(acc0[j] + tr.x);
                float r1 = sigmoidf_(acc1[j] + tr.y);
                float l0 = X[j][c0], l1 = X[j][c0 + 1];
                float q0 = X[j][300 + c0], q1 = X[j][300 + c0 + 1];
                float S0 = l0 + q0, S1 = l1 + q1;
                if (j < NBB) { vS[j][0] = S0; vS[j][1] = S1; }
                else { exch[c0 * NB + j] = S0; exch[(c0 + 1) * NB + j] = S1; }
                X[j][c0] = r0 * l0;        X[j][c0 + 1] = r1 * l1;
                X[j][300 + c0] = r0 * q0;  X[j][300 + c0 + 1] = r1 * q1;
            }
        } else {
            #pragma unroll
            for (int j = 0; j < NB; ++j) {
                int tg = tag_ids[off + node0 + j];
                float2 tz = *(const float2*)&tag_z[tg * H + c0];
                float z0 = sigmoidf_(acc0[j] + tz.x);
                float z1 = sigmoidf_(acc1[j] + tz.y);
                if (j >= NBB) { vZ[j - NBB][0] = z0; vZ[j - NBB][1] = z1; }
                else { exch[c0 * NB + j] = z0; exch[(c0 + 1) * NB + j] = z1; }
            }
        }
    }
    __syncthreads();
    if (act) {
        #pragma unroll
        for (int jj = 0; jj < NBB; ++jj) {
            if (!g) {
                vZ[jj][0] = exch[c0 * NB + jj];
                vZ[jj][1] = exch[(c0 + 1) * NB + jj];
            } else {
                vS[jj][0] = exch[c0 * NB + NBB + jj];
                vS[jj][1] = exch[(c0 + 1) * NB + NBB + jj];
            }
        }
    }
    __syncthreads();   // exchange consumed; Wlds free for phase B staging

    // Phase B
    float accB0[NBB], accB1[NBB];
    #pragma unroll
    for (int jj = 0; jj < NBB; ++jj) { accB0[jj] = 0.f; accB1[jj] = 0.f; }
    int jb = g * NBB;
    stage_panel<1>(Wu + 300 * H, Wu + 300 * H, 0, R, Wlds, tid);
    __syncthreads();
    buf = 0;
    for (int p = 0; p < NP; ++p) {
        if (p + 1 < NP)
            stage_panel<1>(Wu + 300 * H, Wu + 300 * H, (p + 1) * R, R,
                           Wlds + (buf ^ 1) * 2400, tid);
        if (act) {
            const float* wb = Wlds + buf * 2400 + c0;
            float2 wl[R];
            #pragma unroll
            for (int i = 0; i < R; ++i) wl[i] = *(const float2*)&wb[i * 300];
            int kb = p * R;
            #pragma unroll
            for (int jj = 0; jj < NBB; ++jj) {
                float xv[8];
                *(float4*)&xv[0] = *(const float4*)&X[jb + jj][kb];
                *(float4*)&xv[4] = *(const float4*)&X[jb + jj][kb + 4];
                #pragma unroll
                for (int i = 0; i < 8; ++i) {
                    accB0[jj] = fmaf(xv[i], wl[i].x, accB0[jj]);
                    accB1[jj] = fmaf(xv[i], wl[i].y, accB1[jj]);
                }
            }
        }
        __syncthreads();
        buf ^= 1;
    }
    if (act) {
        float b0 = bu[c0], b1 = bu[c0 + 1];
        #pragma unroll
        for (int jj = 0; jj < NBB; ++jj) {
            float u0 = tanhf(accB0[jj] + b0);
            float u1 = tanhf(accB1[jj] + b1);
            float h0 = vZ[jj][0] * vS[jj][0] + (1.f - vZ[jj][0]) * u0;
            float h1 = vZ[jj][1] * vS[jj][1] + (1.f - vZ[jj][1]) * u1;
            *(float2*)&out[(long)(off + node0 + jb + jj) * H + c0] = make_float2(h0, h1);
        }
    }
}

// ---------------- Tail (m<=256): column+K-parallel, 2 kernels per level ----
__global__ __launch_bounds__(320, 1) void tail_gates_k(
    const int* __restrict__ tag_ids,
    const float* __restrict__ Wr, const float* __restrict__ Wz,
    const float* __restrict__ tag_r, const float* __restrict__ tag_z,
    const float* __restrict__ out,
    float* __restrict__ zbuf, float* __restrict__ sbuf, float* __restrict__ rxbuf,
    int off, int prevOff)
{
    __shared__ float X[608];
    __shared__ float redR[3][152];
    __shared__ float redZ[3][152];
    int n  = blockIdx.x >> 1;
    int sl = blockIdx.x & 1;
    int tid = threadIdx.x;

    for (int i = tid; i < 150; i += 320) {
        int half = i / 75, q = i - half * 75;
        *(float4*)&X[half * 300 + q * 4] =
            *(const float4*)&out[(long)(prevOff + 2 * n + half) * H + q * 4];
    }
    __syncthreads();

    int kg = tid / 75;
    int pc = tid - kg * 75;
    bool act = (tid < 300);
    int c0 = sl * 150 + 2 * pc;
    float a0r = 0.f, a1r = 0.f, a0z = 0.f, a1z = 0.f;
    if (act) {
        int ch0 = kg * 19, ch1 = (kg == 3) ? 75 : ch0 + 19;
        const float* wr = Wr + 350 * H + c0;
        const float* wz = Wz + 350 * H + c0;
        for (int ch = ch0; ch < ch1; ++ch) {
            int k = ch * 8;
            float2 wrv[8], wzv[8];
            #pragma unroll
            for (int i = 0; i < 8; ++i) {
                wrv[i] = *(const float2*)&wr[(k + i) * H];
                wzv[i] = *(const float2*)&wz[(k + i) * H];
            }
            #pragma unroll
            for (int i = 0; i < 8; ++i) {
                float xv = X[k + i];
                a0r = fmaf(xv, wrv[i].x, a0r); a1r = fmaf(xv, wrv[i].y, a1r);
                a0z = fmaf(xv, wzv[i].x, a0z); a1z = fmaf(xv, wzv[i].y, a1z);
            }
        }
        if (kg > 0) {
            redR[kg - 1][2 * pc] = a0r; redR[kg - 1][2 * pc + 1] = a1r;
            redZ[kg - 1][2 * pc] = a0z; redZ[kg - 1][2 * pc + 1] = a1z;
        }
    }
    __syncthreads();
    if (act && kg == 0) {
        a0r += redR[0][2 * pc] + redR[1][2 * pc] + redR[2][2 * pc];
        a1r += redR[0][2 * pc + 1] + redR[1][2 * pc + 1] + redR[2][2 * pc + 1];
        a0z += redZ[0][2 * pc] + redZ[1][2 * pc] + redZ[2][2 * pc];
        a1z += redZ[0][2 * pc + 1] + redZ[1][2 * pc + 1] + redZ[2][2 * pc + 1];
        int tg = tag_ids[off + n];
        float r0 = sigmoidf_(a0r + tag_r[tg * H + c0]);
        float r1 = sigmoidf_(a1r + tag_r[tg * H + c0 + 1]);
        float z0 = sigmoidf_(a0z + tag_z[tg * H + c0]);
        float z1 = sigmoidf_(a1z + tag_z[tg * H + c0 + 1]);
        float l0 = X[c0], l1 = X[c0 + 1];
        float q0 = X[300 + c0], q1 = X[300 + c0 + 1];
        *(float2*)&zbuf[n * 304 + c0]  = make_float2(z0, z1);
        *(float2*)&sbuf[n * 304 + c0]  = make_float2(l0 + q0, l1 + q1);
        *(float2*)&rxbuf[n * 608 + c0]       = make_float2(r0 * l0, r1 * l1);
        *(float2*)&rxbuf[n * 608 + 300 + c0] = make_float2(r0 * q0, r1 * q1);
    }
}

__global__ __launch_bounds__(320, 1) void tail_u_k(
    const float* __restrict__ Wu, const float* __restrict__ bu,
    const float* __restrict__ zbuf, const float* __restrict__ sbuf,
    const float* __restrict__ rxbuf,
    float* __restrict__ out, int off, float* __restrict__ dup)
{
    __shared__ float RX[608];
    __shared__ float redU[3][152];
    int n  = blockIdx.x >> 1;
    int sl = blockIdx.x & 1;
    int tid = threadIdx.x;

    for (int i = tid; i < 150; i += 320) {
        int half = i / 75, q = i - half * 75;
        *(float4*)&RX[half * 300 + q * 4] =
            *(const float4*)&rxbuf[n * 608 + half * 300 + q * 4];
    }
    __syncthreads();

    int kg = tid / 75;
    int pc = tid - kg * 75;
    bool act = (tid < 300);
    int c0 = sl * 150 + 2 * pc;
    float a0 = 0.f, a1 = 0.f;
    if (act) {
        int ch0 = kg * 19, ch1 = (kg == 3) ? 75 : ch0 + 19;
        const float* wu = Wu + 300 * H + c0;
        for (int ch = ch0; ch < ch1; ++ch) {
            int k = ch * 8;
            float2 wv[8];
            #pragma unroll
            for (int i = 0; i < 8; ++i) wv[i] = *(const float2*)&wu[(k + i) * H];
            #pragma unroll
            for (int i = 0; i < 8; ++i) {
                float xv = RX[k + i];
                a0 = fmaf(xv, wv[i].x, a0); a1 = fmaf(xv, wv[i].y, a1);
            }
        }
        if (kg > 0) { redU[kg - 1][2 * pc] = a0; redU[kg - 1][2 * pc + 1] = a1; }
    }
    __syncthreads();
    if (act && kg == 0) {
        a0 += redU[0][2 * pc] + redU[1][2 * pc] + redU[2][2 * pc];
        a1 += redU[0][2 * pc + 1] + redU[1][2 * pc + 1] + redU[2][2 * pc + 1];
        float u0 = tanhf(a0 + bu[c0]);
        float u1 = tanhf(a1 + bu[c0 + 1]);
        float z0 = zbuf[n * 304 + c0], z1 = zbuf[n * 304 + c0 + 1];
        float h0 = z0 * sbuf[n * 304 + c0]     + (1.f - z0) * u0;
        float h1 = z1 * sbuf[n * 304 + c0 + 1] + (1.f - z1) * u1;
        *(float2*)&out[(long)(off + n) * H + c0] = make_float2(h0, h1);
        if (dup && n == 0)
            *(float2*)&dup[c0] = make_float2(h0, h1);
    }
}

extern "C" void kernel_launch(void* const* d_in, const int* in_sizes, int n_in,
                              void* d_out, int out_size, void* d_ws, size_t ws_size,
                              hipStream_t stream)
{
    const int*   word_ids   = (const int*)  d_in[0];
    const int*   tag_ids    = (const int*)  d_in[1];
    const float* word_table = (const float*)d_in[2];
    const float* tag_table  = (const float*)d_in[3];
    const float* Wr         = (const float*)d_in[4];
    const float* br         = (const float*)d_in[5];
    const float* Wz         = (const float*)d_in[6];
    const float* bz         = (const float*)d_in[7];
    const float* Wu         = (const float*)d_in[8];
    const float* bu         = (const float*)d_in[9];
    float* out = (float*)d_out;

    float* tag_r = (float*)d_ws;           // 60*300
    float* tag_z = tag_r + 60 * H;         // 60*300
    float* zbuf  = tag_z + 60 * H;         // 256*304
    float* sbuf  = zbuf + 256 * 304;       // 256*304
    float* rxbuf = sbuf + 256 * 304;       // 256*608

    tag_kernel<<<60, 320, 0, stream>>>(tag_table, Wr, br, Wz, bz, tag_r, tag_z);

    leaf_k<<<NLEAF / 8, NTHR, 0, stream>>>(
        word_ids, tag_ids, word_table, Wz, Wu, bu, tag_z, out);

    // Big internal levels, async-staged weights; 1 block/CU law -> grid 256.
    level_k<8><<<256, NTHR, 0, stream>>>(tag_ids, Wr, Wz, Wu, bu, tag_r, tag_z, out, 4096, 0);
    level_k<4><<<256, NTHR, 0, stream>>>(tag_ids, Wr, Wz, Wu, bu, tag_r, tag_z, out, 6144, 4096);
    level_k<2><<<256, NTHR, 0, stream>>>(tag_ids, Wr, Wz, Wu, bu, tag_r, tag_z, out, 7168, 6144);

    // Tail levels m=256..1: two column+K-parallel kernels per level
    float* finalDup = out + (long)8191 * H;
    int off = 7680, prevOff = 7168;
    for (int m = 256; m >= 1; m >>= 1) {
        tail_gates_k<<<2 * m, 320, 0, stream>>>(
            tag_ids, Wr, Wz, tag_r, tag_z, out, zbuf, sbuf, rxbuf, off, prevOff);
        tail_u_k<<<2 * m, 320, 0, stream>>>(
            Wu, bu, zbuf, sbuf, rxbuf, out, off, (m == 1) ? finalDup : nullptr);
        prevOff = off;
        off += m;
    }
}